// Round 1
// baseline (666.871 us; speedup 1.0000x reference)
//
#include <hip/hip_runtime.h>
#include <hip/hip_bf16.h>
#include <math.h>

typedef __attribute__((ext_vector_type(8))) short bf16x8;
typedef __attribute__((ext_vector_type(4))) float f32x4;

#define EPW 8      // edges/nodes per wave
#define WAVES 4    // waves per block (256 threads)
#define XS 40      // staged image row stride in ushorts per pixel (80B, 16B-aligned)
#define WST 296    // staged weight row stride in ushorts per co (592B, 16B-aligned)

__device__ __forceinline__ unsigned short bf16bits(float f) {
    union { __hip_bfloat16 h; unsigned short u; } cv;
    cv.h = __float2bfloat16(f);
    return cv.u;
}

// ---- split staging: global->regs (issue early), regs->LDS (cvt+write late) ----
__device__ __forceinline__ void load_img(const float* __restrict__ g, float* r, int lane) {
    #pragma unroll
    for (int i = 0; i < 32; ++i) r[i] = g[i * 64 + lane];   // coalesced: lane = pixel
}

__device__ __forceinline__ void write_img(const float* r, unsigned short* xw, int lane) {
    #pragma unroll
    for (int i = 0; i < 16; ++i) {
        unsigned int pk = (unsigned int)bf16bits(r[2 * i]) |
                          ((unsigned int)bf16bits(r[2 * i + 1]) << 16);
        *(unsigned int*)&xw[lane * XS + 2 * i] = pk;   // x_t[pix=lane][ci pair]
    }
}

// fp32 OIHW -> bf16 [co][(kh*3+kw)*32 + ci] in LDS
__device__ __forceinline__ void stage_weights(const float* __restrict__ w,
                                              unsigned short* wl, int t) {
    for (int i = t; i < 9216; i += 256) {
        int co  = i / 288;
        int rem = i - co * 288;
        int ci  = rem / 9;
        int khw = rem - ci * 9;
        wl[co * WST + khw * 32 + ci] = bf16bits(w[i]);
    }
}

// One 3x3 conv as GEMM: C[32co x 64pix] = W[32 x 288] * im2col[288 x 64].
__device__ __forceinline__ void conv_mfma(const unsigned short* __restrict__ xw,
                                          const unsigned short* __restrict__ wl,
                                          int m, int quad, f32x4 acc[2][4]) {
    #pragma unroll
    for (int kb = 0; kb < 9; ++kb) {
        const int kh = kb / 3, kw = kb - kh * 3;
        bf16x8 a0 = *(const bf16x8*)&wl[ m        * WST + kb * 32 + quad * 8];
        bf16x8 a1 = *(const bf16x8*)&wl[(m + 16)  * WST + kb * 32 + quad * 8];
        #pragma unroll
        for (int nt = 0; nt < 4; ++nt) {
            const int p  = nt * 16 + m;
            const int ih = (p >> 3) + kh - 1;
            const int iw = (p & 7) + kw - 1;
            const bool valid = ((unsigned)ih < 8u) && ((unsigned)iw < 8u);
            const int pixp = valid ? (ih * 8 + iw) : 0;
            bf16x8 b = *(const bf16x8*)&xw[pixp * XS + quad * 8];
            if (!valid) b = (bf16x8)(short)0;
            acc[0][nt] = __builtin_amdgcn_mfma_f32_16x16x32_bf16(a0, b, acc[0][nt], 0, 0, 0);
            acc[1][nt] = __builtin_amdgcn_mfma_f32_16x16x32_bf16(a1, b, acc[1][nt], 0, 0, 0);
        }
    }
}

// ---------------- Phase 1: th[node] = conv3x3(input[node], w_node) ----------------
// th stored TRANSPOSED per node: [node][pix][co] fp32, so phase 2 gathers dwordx4
// fragments that land directly in the accumulator (co=quad*4+r) layout.
__global__ __launch_bounds__(256, 3)
void node_conv_kernel(const float* __restrict__ input,
                      const float* __restrict__ w_node,
                      float* __restrict__ th, int n_nodes)
{
    __shared__ __align__(16) unsigned short w_lds[32 * WST];
    __shared__ __align__(16) unsigned short x_lds[WAVES][64 * XS];

    const int t = threadIdx.x, lane = t & 63, wave = t >> 6;
    stage_weights(w_node, w_lds, t);
    __syncthreads();

    const int m = lane & 15, quad = lane >> 4;
    unsigned short* xw = x_lds[wave];
    const int n0 = (blockIdx.x * WAVES + wave) * EPW;

    float ereg[32];
    if (n0 < n_nodes) load_img(input + (size_t)n0 * 2048, ereg, lane);

    for (int j = 0; j < EPW; ++j) {
        const int nd = n0 + j;
        if (nd >= n_nodes) break;   // wave-uniform

        write_img(ereg, xw, lane);
        if (j + 1 < EPW && nd + 1 < n_nodes)
            load_img(input + (size_t)(nd + 1) * 2048, ereg, lane);   // prefetch under conv

        f32x4 acc[2][4];
        #pragma unroll
        for (int a = 0; a < 2; ++a)
            #pragma unroll
            for (int b = 0; b < 4; ++b) acc[a][b] = (f32x4)0.f;

        conv_mfma(xw, w_lds, m, quad, acc);

        float* op = th + (size_t)nd * 2048;
        #pragma unroll
        for (int mt = 0; mt < 2; ++mt)
            #pragma unroll
            for (int nt = 0; nt < 4; ++nt) {
                const int p = nt * 16 + m;
                *(f32x4*)&op[p * 32 + mt * 16 + quad * 4] = acc[mt][nt];  // [pix][co]
            }
    }
}

// ---------------- Phase 2: out[edge] = elu(th[src[edge]] * conv3x3(e, w_edge)) ----------------
__global__ __launch_bounds__(256, 3)
void edge_mul_kernel(const float* __restrict__ e,
                     const int* __restrict__ srcv,
                     const float* __restrict__ th,
                     const float* __restrict__ w_edge,
                     float* __restrict__ out, int n_edges)
{
    __shared__ __align__(16) unsigned short w_lds[32 * WST];     // w_edge only, 18.5 KB
    __shared__ __align__(16) unsigned short x_lds[WAVES][64 * XS]; // 20 KB -> 39.4 KB/block

    const int t = threadIdx.x, lane = t & 63, wave = t >> 6;
    stage_weights(w_edge, w_lds, t);
    __syncthreads();

    const int m = lane & 15, quad = lane >> 4;
    unsigned short* xw = x_lds[wave];
    const int img0 = (blockIdx.x * WAVES + wave) * EPW;

    float ereg[32];
    if (img0 < n_edges) load_img(e + (size_t)img0 * 2048, ereg, lane);

    for (int j = 0; j < EPW; ++j) {
        const int img = img0 + j;
        if (img >= n_edges) break;   // wave-uniform

        write_img(ereg, xw, lane);   // regs (loaded long ago) -> LDS

        // th gather: 8 dwordx4, issued BEFORE conv so LLC latency hides under MFMAs.
        const int src = srcv[img];   // wave-uniform scalar load
        const float* tp = th + (size_t)src * 2048;
        f32x4 T[2][4];
        #pragma unroll
        for (int mt = 0; mt < 2; ++mt)
            #pragma unroll
            for (int nt = 0; nt < 4; ++nt)
                T[mt][nt] = *(const f32x4*)&tp[(nt * 16 + m) * 32 + mt * 16 + quad * 4];

        // prefetch next e image into regs; HBM latency hides under conv.
        if (j + 1 < EPW && img + 1 < n_edges)
            load_img(e + (size_t)(img + 1) * 2048, ereg, lane);

        f32x4 acc[2][4];
        #pragma unroll
        for (int a = 0; a < 2; ++a)
            #pragma unroll
            for (int b = 0; b < 4; ++b) acc[a][b] = (f32x4)0.f;

        conv_mfma(xw, w_lds, m, quad, acc);

        // out = elu(th * z); C/D layout: row(co)=quad*4+r (+16mt), col(pix)=m (+16nt)
        float* op = out + (size_t)img * 2048;
        #pragma unroll
        for (int mt = 0; mt < 2; ++mt)
            #pragma unroll
            for (int nt = 0; nt < 4; ++nt)
                #pragma unroll
                for (int r = 0; r < 4; ++r) {
                    const int co = mt * 16 + quad * 4 + r;
                    const int p  = nt * 16 + m;
                    float v = T[mt][nt][r] * acc[mt][nt][r];
                    op[co * 64 + p] = v > 0.f ? v : (__expf(v) - 1.f);
                }
    }
}

// ---------------- Fallback: proven fused kernel (used only if ws too small) ----------------
__global__ __launch_bounds__(256, 2)
void fused_edge_kernel(const float* __restrict__ input,
                       const int* __restrict__ srcv,
                       const float* __restrict__ e,
                       const float* __restrict__ w_node,
                       const float* __restrict__ w_edge,
                       float* __restrict__ out,
                       int n_edges)
{
    __shared__ __align__(16) unsigned short w_lds[2][32 * WST];
    __shared__ __align__(16) unsigned short x_lds[WAVES][64 * XS];

    const int t = threadIdx.x;
    const int lane = t & 63;
    const int wave = t >> 6;

    for (int i = t; i < 9216; i += 256) {
        int co  = i / 288;
        int rem = i - co * 288;
        int ci  = rem / 9;
        int khw = rem - ci * 9;
        int dst = co * WST + khw * 32 + ci;
        w_lds[0][dst] = bf16bits(w_edge[i]);
        w_lds[1][dst] = bf16bits(w_node[i]);
    }
    __syncthreads();

    const int m    = lane & 15;
    const int quad = lane >> 4;
    unsigned short* xw = x_lds[wave];

    const int img0 = (blockIdx.x * WAVES + wave) * EPW;

    for (int j = 0; j < EPW; ++j) {
        const int img = img0 + j;
        if (img >= n_edges) break;

        f32x4 accz[2][4], acct[2][4];
        #pragma unroll
        for (int a = 0; a < 2; ++a)
            #pragma unroll
            for (int b = 0; b < 4; ++b) { accz[a][b] = (f32x4)0.f; acct[a][b] = (f32x4)0.f; }

        float ereg[32];
        load_img(e + (size_t)img * 2048, ereg, lane);
        write_img(ereg, xw, lane);
        conv_mfma(xw, w_lds[0], m, quad, accz);

        load_img(input + (size_t)srcv[img] * 2048, ereg, lane);
        write_img(ereg, xw, lane);
        conv_mfma(xw, w_lds[1], m, quad, acct);

        float* op = out + (size_t)img * 2048;
        #pragma unroll
        for (int mt = 0; mt < 2; ++mt)
            #pragma unroll
            for (int nt = 0; nt < 4; ++nt)
                #pragma unroll
                for (int r = 0; r < 4; ++r) {
                    const int co = mt * 16 + quad * 4 + r;
                    const int p  = nt * 16 + m;
                    float v = accz[mt][nt][r] * acct[mt][nt][r];
                    op[co * 64 + p] = v > 0.f ? v : (__expf(v) - 1.f);
                }
    }
}

extern "C" void kernel_launch(void* const* d_in, const int* in_sizes, int n_in,
                              void* d_out, int out_size, void* d_ws, size_t ws_size,
                              hipStream_t stream)
{
    // setup_inputs order: input, edge_sources, e, w_node, w_edge
    const float* input        = (const float*)d_in[0];
    const int*   edge_sources = (const int*)  d_in[1];
    const float* e            = (const float*)d_in[2];
    const float* w_node       = (const float*)d_in[3];
    const float* w_edge       = (const float*)d_in[4];
    float* out = (float*)d_out;

    const int n_edges = in_sizes[1];                        // 32768
    // in_sizes convention ambiguity: element-count (4096*2048) vs first-dim (4096)
    const int n_nodes = in_sizes[0] > 65536 ? in_sizes[0] / 2048 : in_sizes[0];

    const int per_block = WAVES * EPW;                      // 32 images per block
    const int egrid = (n_edges + per_block - 1) / per_block;

    const size_t th_bytes = (size_t)n_nodes * 2048 * sizeof(float);   // 32 MB @4096 nodes

    if (d_ws != nullptr && ws_size >= th_bytes) {
        // Two-phase: node conv once (4096 convs) instead of per-edge (32768 convs).
        // Strictly within ws bounds (prior session's overrun hazard guarded here).
        float* th = (float*)d_ws;
        const int ngrid = (n_nodes + per_block - 1) / per_block;
        node_conv_kernel<<<dim3(ngrid), dim3(256), 0, stream>>>(input, w_node, th, n_nodes);
        edge_mul_kernel<<<dim3(egrid), dim3(256), 0, stream>>>(e, edge_sources, th, w_edge,
                                                               out, n_edges);
    } else {
        fused_edge_kernel<<<dim3(egrid), dim3(256), 0, stream>>>(
            input, edge_sources, e, w_node, w_edge, out, n_edges);
    }
}